// Round 1
// baseline (1389.630 us; speedup 1.0000x reference)
//
#include <hip/hip_runtime.h>
#include <hip/hip_bf16.h>

using bf16x8 = __attribute__((ext_vector_type(8))) short;
using f32x4  = __attribute__((ext_vector_type(4))) float;
typedef unsigned short u16;
typedef unsigned int u32;

#define NB    2
#define NC    128
#define ND    64
#define NH    64
#define NW    64
#define NPTS  65536
#define MTOT  (NB*NPTS)     // 131072
#define H1D   512
#define H2D   512

// round-to-nearest-even fp32 -> bf16 (bit pattern)
static __device__ __forceinline__ u16 f2bf(float f) {
    u32 u = __float_as_uint(f);
    u32 r = (u + 0x7FFFu + ((u >> 16) & 1u)) >> 16;
    return (u16)r;
}

// ---------------- prep: transpose+cast weights, fold BN ----------------
__global__ void prep_kernel(
    const float* __restrict__ W1, const float* __restrict__ W2,
    const float* __restrict__ b1, const float* __restrict__ g1, const float* __restrict__ be1,
    const float* __restrict__ m1, const float* __restrict__ v1,
    const float* __restrict__ b2, const float* __restrict__ g2, const float* __restrict__ be2,
    const float* __restrict__ m2, const float* __restrict__ v2,
    u16* __restrict__ W1t, u16* __restrict__ W2t,
    float* __restrict__ s1, float* __restrict__ t1,
    float* __restrict__ s2, float* __restrict__ t2)
{
    int id = blockIdx.x * 256 + threadIdx.x;          // 0 .. 262143
    {   // W2t[n][c] = W2[c][n], 512x512
        int c = id & 511, n = id >> 9;
        W2t[n * 512 + c] = f2bf(W2[c * 512 + n]);
    }
    if (id < NC * H1D) {  // W1t[n][c] = W1[c][n], (512 x 128)
        int c = id & 127, n = id >> 7;
        W1t[n * 128 + c] = f2bf(W1[c * 512 + n]);
    }
    if (id < 512) {
        float s = g1[id] * rsqrtf(v1[id] + 1e-5f);
        s1[id] = s;
        t1[id] = (b1[id] - m1[id]) * s + be1[id];
        float s2_ = g2[id] * rsqrtf(v2[id] + 1e-5f);
        s2[id] = s2_;
        t2[id] = (b2[id] - m2[id]) * s2_ + be2[id];
    }
}

// ---------------- trilinear sampling ----------------
// 1 thread per (point, channel). feats_out[point][channel] bf16.
__global__ void sample_kernel(const float* __restrict__ feat,
                              const float* __restrict__ qp,
                              u16* __restrict__ fo)
{
    int tid = blockIdx.x * 256 + threadIdx.x;
    int p = tid >> 7;          // 0 .. 131071
    int c = tid & 127;
    int b = p >> 16;

    float qx = qp[p * 3 + 0];
    float qy = qp[p * 3 + 1];
    float qz = qp[p * 3 + 2];
    // grid = 2q-1; unnorm: (g+1)*0.5*(dim-1) = q*(dim-1); border = clamp
    float x = fminf(fmaxf(qx * 63.0f, 0.0f), 63.0f);
    float y = fminf(fmaxf(qy * 63.0f, 0.0f), 63.0f);
    float z = fminf(fmaxf(qz * 63.0f, 0.0f), 63.0f);
    int x0 = (int)floorf(x), y0 = (int)floorf(y), z0 = (int)floorf(z);
    int x1 = min(x0 + 1, 63), y1 = min(y0 + 1, 63), z1 = min(z0 + 1, 63);
    float wx = x - (float)x0, wy = y - (float)y0, wz = z - (float)z0;

    const float* fb = feat + ((size_t)(b * NC + c) << 18);   // * 64*64*64
    int zy00 = z0 * 4096 + y0 * 64;
    int zy01 = z0 * 4096 + y1 * 64;
    int zy10 = z1 * 4096 + y0 * 64;
    int zy11 = z1 * 4096 + y1 * 64;
    float f000 = fb[zy00 + x0], f001 = fb[zy00 + x1];
    float f010 = fb[zy01 + x0], f011 = fb[zy01 + x1];
    float f100 = fb[zy10 + x0], f101 = fb[zy10 + x1];
    float f110 = fb[zy11 + x0], f111 = fb[zy11 + x1];

    float omx = 1.0f - wx;
    float c00 = f000 * omx + f001 * wx;
    float c01 = f010 * omx + f011 * wx;
    float c10 = f100 * omx + f101 * wx;
    float c11 = f110 * omx + f111 * wx;
    float omy = 1.0f - wy;
    float c0 = c00 * omy + c01 * wy;
    float c1 = c10 * omy + c11 * wy;
    float v  = c0 * (1.0f - wz) + c1 * wz;

    fo[(size_t)p * 128 + c] = f2bf(v);
}

// ---------------- fused MLP: (feats @ W1 ->BN/ReLU) @ W2 ->BN/ReLU @ W3 + b3 ----
// block = 256 threads = 4 waves; tile = 64 points. Wave w owns output cols [128w,128w+128).
__global__ __launch_bounds__(256, 2) void mlp_kernel(
    const u16* __restrict__ feats, const u16* __restrict__ W1t, const u16* __restrict__ W2t,
    const float* __restrict__ s1, const float* __restrict__ t1,
    const float* __restrict__ s2, const float* __restrict__ t2,
    const float* __restrict__ W3, const float* __restrict__ b3,
    float* __restrict__ out)
{
    __shared__ u16 h1[64 * 512];          // 64 KiB; reused as float outb[256] at the end
    float* outb = (float*)h1;

    const int tidx = threadIdx.x;
    const int w    = tidx >> 6;
    const int l    = tidx & 63;
    const int l15  = l & 15;
    const int lq   = l >> 4;
    const int kq   = lq * 8;
    const int m0   = blockIdx.x * 64;
    const int n0   = w * 128;

    // ---- GEMM1: h1 = feats(64x128) @ W1(128x512) ----
    f32x4 acc[4][8];
    #pragma unroll
    for (int i = 0; i < 4; ++i)
        #pragma unroll
        for (int j = 0; j < 8; ++j) acc[i][j] = (f32x4){0.f, 0.f, 0.f, 0.f};

    #pragma unroll
    for (int kk = 0; kk < 4; ++kk) {
        const int kb = kk * 32 + kq;
        bf16x8 a[4], bb[8];
        #pragma unroll
        for (int mf = 0; mf < 4; ++mf)
            a[mf] = *(const bf16x8*)(feats + (size_t)(m0 + mf * 16 + l15) * 128 + kb);
        #pragma unroll
        for (int nf = 0; nf < 8; ++nf)
            bb[nf] = *(const bf16x8*)(W1t + (n0 + nf * 16 + l15) * 128 + kb);
        #pragma unroll
        for (int mf = 0; mf < 4; ++mf)
            #pragma unroll
            for (int nf = 0; nf < 8; ++nf)
                acc[mf][nf] = __builtin_amdgcn_mfma_f32_16x16x32_bf16(a[mf], bb[nf], acc[mf][nf], 0, 0, 0);
    }

    // ---- BN1 + ReLU -> h1 in LDS, XOR-swizzled (16B-chunk ^ (row&7)) ----
    {
        float s1v[8], t1v[8];
        #pragma unroll
        for (int nf = 0; nf < 8; ++nf) {
            int col = n0 + nf * 16 + l15;
            s1v[nf] = s1[col]; t1v[nf] = t1[col];
        }
        #pragma unroll
        for (int mf = 0; mf < 4; ++mf)
            #pragma unroll
            for (int nf = 0; nf < 8; ++nf) {
                int col = n0 + nf * 16 + l15;
                #pragma unroll
                for (int i = 0; i < 4; ++i) {
                    int row = mf * 16 + lq * 4 + i;     // C/D map: col=lane&15, row=(lane>>4)*4+i
                    float v = fmaxf(acc[mf][nf][i] * s1v[nf] + t1v[nf], 0.0f);
                    h1[row * 512 + (col ^ ((row & 7) << 3))] = f2bf(v);
                }
            }
    }
    __syncthreads();

    // ---- GEMM2: h2 = h1(64x512) @ W2(512x512) ----
    f32x4 acc2[4][8];
    #pragma unroll
    for (int i = 0; i < 4; ++i)
        #pragma unroll
        for (int j = 0; j < 8; ++j) acc2[i][j] = (f32x4){0.f, 0.f, 0.f, 0.f};

    for (int kk = 0; kk < 16; ++kk) {
        const int kb = kk * 32 + kq;
        bf16x8 a[4], bb[8];
        #pragma unroll
        for (int mf = 0; mf < 4; ++mf) {
            int row = mf * 16 + l15;
            a[mf] = *(const bf16x8*)(h1 + row * 512 + (kb ^ ((row & 7) << 3)));
        }
        #pragma unroll
        for (int nf = 0; nf < 8; ++nf)
            bb[nf] = *(const bf16x8*)(W2t + (size_t)(n0 + nf * 16 + l15) * 512 + kb);
        #pragma unroll
        for (int mf = 0; mf < 4; ++mf)
            #pragma unroll
            for (int nf = 0; nf < 8; ++nf)
                acc2[mf][nf] = __builtin_amdgcn_mfma_f32_16x16x32_bf16(a[mf], bb[nf], acc2[mf][nf], 0, 0, 0);
    }

    // ---- BN2 + ReLU + final dot with W3 (fp32) ----
    float part[16];
    #pragma unroll
    for (int i = 0; i < 16; ++i) part[i] = 0.f;
    {
        float s2v[8], t2v[8], w3v[8];
        #pragma unroll
        for (int nf = 0; nf < 8; ++nf) {
            int col = n0 + nf * 16 + l15;
            s2v[nf] = s2[col]; t2v[nf] = t2[col]; w3v[nf] = W3[col];
        }
        #pragma unroll
        for (int mf = 0; mf < 4; ++mf)
            #pragma unroll
            for (int nf = 0; nf < 8; ++nf)
                #pragma unroll
                for (int i = 0; i < 4; ++i) {
                    float h = fmaxf(acc2[mf][nf][i] * s2v[nf] + t2v[nf], 0.0f);
                    part[mf * 4 + i] += h * w3v[nf];
                }
    }
    // reduce across the 16 column-lanes
    #pragma unroll
    for (int off = 1; off < 16; off <<= 1)
        #pragma unroll
        for (int i = 0; i < 16; ++i) part[i] += __shfl_xor(part[i], off, 64);

    __syncthreads();   // all h1 reads done before aliasing as outb
    if (l15 == 0) {
        #pragma unroll
        for (int mf = 0; mf < 4; ++mf)
            #pragma unroll
            for (int i = 0; i < 4; ++i)
                outb[w * 64 + mf * 16 + lq * 4 + i] = part[mf * 4 + i];
    }
    __syncthreads();
    if (tidx < 64) {
        float r = outb[tidx] + outb[64 + tidx] + outb[128 + tidx] + outb[192 + tidx] + b3[0];
        out[m0 + tidx] = r;
    }
}

extern "C" void kernel_launch(void* const* d_in, const int* in_sizes, int n_in,
                              void* d_out, int out_size, void* d_ws, size_t ws_size,
                              hipStream_t stream)
{
    const float* feat = (const float*)d_in[0];
    const float* qp   = (const float*)d_in[1];
    const float* W1   = (const float*)d_in[2];
    const float* b1   = (const float*)d_in[3];
    const float* g1   = (const float*)d_in[4];
    const float* be1  = (const float*)d_in[5];
    const float* m1   = (const float*)d_in[6];
    const float* v1   = (const float*)d_in[7];
    const float* W2   = (const float*)d_in[8];
    const float* b2   = (const float*)d_in[9];
    const float* g2   = (const float*)d_in[10];
    const float* be2  = (const float*)d_in[11];
    const float* m2   = (const float*)d_in[12];
    const float* v2   = (const float*)d_in[13];
    const float* W3   = (const float*)d_in[14];
    const float* b3   = (const float*)d_in[15];

    char* ws = (char*)d_ws;
    u16*   W1t   = (u16*)(ws);                    // 131072 B
    u16*   W2t   = (u16*)(ws + 131072);           // 524288 B
    float* s1    = (float*)(ws + 655360);         // 2048 B
    float* t1    = (float*)(ws + 657408);
    float* s2    = (float*)(ws + 659456);
    float* t2    = (float*)(ws + 661504);
    u16*   feats = (u16*)(ws + 663552);           // 131072*128*2 = 33554432 B

    prep_kernel<<<1024, 256, 0, stream>>>(W1, W2, b1, g1, be1, m1, v1,
                                          b2, g2, be2, m2, v2,
                                          W1t, W2t, s1, t1, s2, t2);
    sample_kernel<<<(MTOT * 128) / 256, 256, 0, stream>>>(feat, qp, feats);
    mlp_kernel<<<MTOT / 64, 256, 0, stream>>>(feats, W1t, W2t, s1, t1, s2, t2,
                                              W3, b3, (float*)d_out);
}

// Round 2
// 301.662 us; speedup vs baseline: 4.6066x; 4.6066x over previous
//
#include <hip/hip_runtime.h>
#include <hip/hip_bf16.h>

using bf16x8 = __attribute__((ext_vector_type(8))) short;
using f32x4  = __attribute__((ext_vector_type(4))) float;
typedef unsigned short u16;
typedef unsigned int u32;

#define NB    2
#define NC    128
#define NVOX  262144        // 64*64*64
#define NPTS  65536
#define MTOT  (NB*NPTS)     // 131072
#define H1D   512
#define H2D   512

// round-to-nearest-even fp32 -> bf16 (bit pattern)
static __device__ __forceinline__ u16 f2bf(float f) {
    u32 u = __float_as_uint(f);
    u32 r = (u + 0x7FFFu + ((u >> 16) & 1u)) >> 16;
    return (u16)r;
}
static __device__ __forceinline__ float bflo(u32 d) { return __uint_as_float(d << 16); }
static __device__ __forceinline__ float bfhi(u32 d) { return __uint_as_float(d & 0xFFFF0000u); }

// ---------------- prep: transpose+cast weights, fold BN ----------------
__global__ void prep_kernel(
    const float* __restrict__ W1, const float* __restrict__ W2,
    const float* __restrict__ b1, const float* __restrict__ g1, const float* __restrict__ be1,
    const float* __restrict__ m1, const float* __restrict__ v1,
    const float* __restrict__ b2, const float* __restrict__ g2, const float* __restrict__ be2,
    const float* __restrict__ m2, const float* __restrict__ v2,
    u16* __restrict__ W1t, u16* __restrict__ W2t,
    float* __restrict__ s1, float* __restrict__ t1,
    float* __restrict__ s2, float* __restrict__ t2)
{
    int id = blockIdx.x * 256 + threadIdx.x;          // 0 .. 262143
    {   // W2t[n][c] = W2[c][n], 512x512
        int c = id & 511, n = id >> 9;
        W2t[n * 512 + c] = f2bf(W2[c * 512 + n]);
    }
    if (id < NC * H1D) {  // W1t[n][c] = W1[c][n], (512 x 128)
        int c = id & 127, n = id >> 7;
        W1t[n * 128 + c] = f2bf(W1[c * 512 + n]);
    }
    if (id < 512) {
        float s = g1[id] * rsqrtf(v1[id] + 1e-5f);
        s1[id] = s;
        t1[id] = (b1[id] - m1[id]) * s + be1[id];
        float s2_ = g2[id] * rsqrtf(v2[id] + 1e-5f);
        s2[id] = s2_;
        t2[id] = (b2[id] - m2[id]) * s2_ + be2[id];
    }
}

// ---------------- volume transpose: (B,C,64^3) f32 -> (B,64^3,C) bf16 ----------------
// 32 voxels x 128 channels per block. LDS pad 33 keeps both sides ~conflict-free.
__global__ __launch_bounds__(256) void transpose_kernel(const float* __restrict__ feat,
                                                        u16* __restrict__ featT)
{
    __shared__ float tile[128][33];
    int blk = blockIdx.x;               // 0..16383
    int b   = blk >> 13;                // 8192 blocks per batch
    int v0  = (blk & 8191) << 5;        // *32
    int t   = threadIdx.x;
    int vi  = t & 31;
    int c0  = t >> 5;                   // 0..7
    const float* fb = feat + ((size_t)b << 25);   // b * 128 * 262144
    #pragma unroll
    for (int r = 0; r < 16; ++r) {
        int c = c0 + 8 * r;
        tile[c][vi] = fb[((size_t)c << 18) + v0 + vi];
    }
    __syncthreads();
    u32* outp = (u32*)(featT + (((size_t)b << 18) + v0) * 128);
    #pragma unroll
    for (int r = 0; r < 8; ++r) {
        int w  = t + 256 * r;           // 0..2047 u32s
        int v  = w >> 6;
        int cp = w & 63;
        float lo = tile[2 * cp][v], hi = tile[2 * cp + 1][v];
        outp[w] = (u32)f2bf(lo) | ((u32)f2bf(hi) << 16);
    }
}

// ---------------- trilinear sampling, channel-last ----------------
// 64 lanes per point, 2 channels per lane (u32 = bf16x2). Corner read = 256B coalesced.
__global__ __launch_bounds__(256) void sampleT_kernel(const u16* __restrict__ featT,
                                                      const float* __restrict__ qp,
                                                      u16* __restrict__ fo)
{
    int tid = blockIdx.x * 256 + threadIdx.x;
    int p   = tid >> 6;          // 0 .. 131071
    int cp  = tid & 63;          // channel pair
    int b   = p >> 16;

    float qx = qp[p * 3 + 0];
    float qy = qp[p * 3 + 1];
    float qz = qp[p * 3 + 2];
    float x = fminf(fmaxf(qx * 63.0f, 0.0f), 63.0f);
    float y = fminf(fmaxf(qy * 63.0f, 0.0f), 63.0f);
    float z = fminf(fmaxf(qz * 63.0f, 0.0f), 63.0f);
    int x0 = (int)floorf(x), y0 = (int)floorf(y), z0 = (int)floorf(z);
    int x1 = min(x0 + 1, 63), y1 = min(y0 + 1, 63), z1 = min(z0 + 1, 63);
    float wx = x - (float)x0, wy = y - (float)y0, wz = z - (float)z0;

    const u32* fb = (const u32*)featT + (((size_t)b << 18) << 6);  // *64 u32/voxel
    int zy00 = z0 * 4096 + y0 * 64, zy01 = z0 * 4096 + y1 * 64;
    int zy10 = z1 * 4096 + y0 * 64, zy11 = z1 * 4096 + y1 * 64;
    u32 d000 = fb[(size_t)(zy00 + x0) * 64 + cp];
    u32 d001 = fb[(size_t)(zy00 + x1) * 64 + cp];
    u32 d010 = fb[(size_t)(zy01 + x0) * 64 + cp];
    u32 d011 = fb[(size_t)(zy01 + x1) * 64 + cp];
    u32 d100 = fb[(size_t)(zy10 + x0) * 64 + cp];
    u32 d101 = fb[(size_t)(zy10 + x1) * 64 + cp];
    u32 d110 = fb[(size_t)(zy11 + x0) * 64 + cp];
    u32 d111 = fb[(size_t)(zy11 + x1) * 64 + cp];

    float omx = 1.0f - wx, omy = 1.0f - wy, omz = 1.0f - wz;
    float rl, rh;
    {
        float c00 = bflo(d000) * omx + bflo(d001) * wx;
        float c01 = bflo(d010) * omx + bflo(d011) * wx;
        float c10 = bflo(d100) * omx + bflo(d101) * wx;
        float c11 = bflo(d110) * omx + bflo(d111) * wx;
        rl = (c00 * omy + c01 * wy) * omz + (c10 * omy + c11 * wy) * wz;
    }
    {
        float c00 = bfhi(d000) * omx + bfhi(d001) * wx;
        float c01 = bfhi(d010) * omx + bfhi(d011) * wx;
        float c10 = bfhi(d100) * omx + bfhi(d101) * wx;
        float c11 = bfhi(d110) * omx + bfhi(d111) * wx;
        rh = (c00 * omy + c01 * wy) * omz + (c10 * omy + c11 * wy) * wz;
    }
    ((u32*)fo)[(size_t)p * 64 + cp] = (u32)f2bf(rl) | ((u32)f2bf(rh) << 16);
}

// ---------------- fallback scattered sampler (if ws too small) ----------------
__global__ void sample_kernel(const float* __restrict__ feat,
                              const float* __restrict__ qp,
                              u16* __restrict__ fo)
{
    int tid = blockIdx.x * 256 + threadIdx.x;
    int p = tid >> 7;
    int c = tid & 127;
    int b = p >> 16;

    float qx = qp[p * 3 + 0], qy = qp[p * 3 + 1], qz = qp[p * 3 + 2];
    float x = fminf(fmaxf(qx * 63.0f, 0.0f), 63.0f);
    float y = fminf(fmaxf(qy * 63.0f, 0.0f), 63.0f);
    float z = fminf(fmaxf(qz * 63.0f, 0.0f), 63.0f);
    int x0 = (int)floorf(x), y0 = (int)floorf(y), z0 = (int)floorf(z);
    int x1 = min(x0 + 1, 63), y1 = min(y0 + 1, 63), z1 = min(z0 + 1, 63);
    float wx = x - (float)x0, wy = y - (float)y0, wz = z - (float)z0;

    const float* fb = feat + ((size_t)(b * NC + c) << 18);
    int zy00 = z0 * 4096 + y0 * 64, zy01 = z0 * 4096 + y1 * 64;
    int zy10 = z1 * 4096 + y0 * 64, zy11 = z1 * 4096 + y1 * 64;
    float f000 = fb[zy00 + x0], f001 = fb[zy00 + x1];
    float f010 = fb[zy01 + x0], f011 = fb[zy01 + x1];
    float f100 = fb[zy10 + x0], f101 = fb[zy10 + x1];
    float f110 = fb[zy11 + x0], f111 = fb[zy11 + x1];

    float omx = 1.0f - wx;
    float c00 = f000 * omx + f001 * wx;
    float c01 = f010 * omx + f011 * wx;
    float c10 = f100 * omx + f101 * wx;
    float c11 = f110 * omx + f111 * wx;
    float omy = 1.0f - wy;
    float c0 = c00 * omy + c01 * wy;
    float c1 = c10 * omy + c11 * wy;
    float v  = c0 * (1.0f - wz) + c1 * wz;
    fo[(size_t)p * 128 + c] = f2bf(v);
}

// ---------------- fused MLP ----------------
__global__ __launch_bounds__(256, 2) void mlp_kernel(
    const u16* __restrict__ feats, const u16* __restrict__ W1t, const u16* __restrict__ W2t,
    const float* __restrict__ s1, const float* __restrict__ t1,
    const float* __restrict__ s2, const float* __restrict__ t2,
    const float* __restrict__ W3, const float* __restrict__ b3,
    float* __restrict__ out)
{
    __shared__ u16 h1[64 * 512];
    float* outb = (float*)h1;

    const int tidx = threadIdx.x;
    const int w    = tidx >> 6;
    const int l    = tidx & 63;
    const int l15  = l & 15;
    const int lq   = l >> 4;
    const int kq   = lq * 8;
    const int m0   = blockIdx.x * 64;
    const int n0   = w * 128;

    f32x4 acc[4][8];
    #pragma unroll
    for (int i = 0; i < 4; ++i)
        #pragma unroll
        for (int j = 0; j < 8; ++j) acc[i][j] = (f32x4){0.f, 0.f, 0.f, 0.f};

    #pragma unroll
    for (int kk = 0; kk < 4; ++kk) {
        const int kb = kk * 32 + kq;
        bf16x8 a[4], bb[8];
        #pragma unroll
        for (int mf = 0; mf < 4; ++mf)
            a[mf] = *(const bf16x8*)(feats + (size_t)(m0 + mf * 16 + l15) * 128 + kb);
        #pragma unroll
        for (int nf = 0; nf < 8; ++nf)
            bb[nf] = *(const bf16x8*)(W1t + (n0 + nf * 16 + l15) * 128 + kb);
        #pragma unroll
        for (int mf = 0; mf < 4; ++mf)
            #pragma unroll
            for (int nf = 0; nf < 8; ++nf)
                acc[mf][nf] = __builtin_amdgcn_mfma_f32_16x16x32_bf16(a[mf], bb[nf], acc[mf][nf], 0, 0, 0);
    }

    {
        float s1v[8], t1v[8];
        #pragma unroll
        for (int nf = 0; nf < 8; ++nf) {
            int col = n0 + nf * 16 + l15;
            s1v[nf] = s1[col]; t1v[nf] = t1[col];
        }
        #pragma unroll
        for (int mf = 0; mf < 4; ++mf)
            #pragma unroll
            for (int nf = 0; nf < 8; ++nf) {
                int col = n0 + nf * 16 + l15;
                #pragma unroll
                for (int i = 0; i < 4; ++i) {
                    int row = mf * 16 + lq * 4 + i;
                    float v = fmaxf(acc[mf][nf][i] * s1v[nf] + t1v[nf], 0.0f);
                    h1[row * 512 + (col ^ ((row & 7) << 3))] = f2bf(v);
                }
            }
    }
    __syncthreads();

    f32x4 acc2[4][8];
    #pragma unroll
    for (int i = 0; i < 4; ++i)
        #pragma unroll
        for (int j = 0; j < 8; ++j) acc2[i][j] = (f32x4){0.f, 0.f, 0.f, 0.f};

    for (int kk = 0; kk < 16; ++kk) {
        const int kb = kk * 32 + kq;
        bf16x8 a[4], bb[8];
        #pragma unroll
        for (int mf = 0; mf < 4; ++mf) {
            int row = mf * 16 + l15;
            a[mf] = *(const bf16x8*)(h1 + row * 512 + (kb ^ ((row & 7) << 3)));
        }
        #pragma unroll
        for (int nf = 0; nf < 8; ++nf)
            bb[nf] = *(const bf16x8*)(W2t + (size_t)(n0 + nf * 16 + l15) * 512 + kb);
        #pragma unroll
        for (int mf = 0; mf < 4; ++mf)
            #pragma unroll
            for (int nf = 0; nf < 8; ++nf)
                acc2[mf][nf] = __builtin_amdgcn_mfma_f32_16x16x32_bf16(a[mf], bb[nf], acc2[mf][nf], 0, 0, 0);
    }

    float part[16];
    #pragma unroll
    for (int i = 0; i < 16; ++i) part[i] = 0.f;
    {
        float s2v[8], t2v[8], w3v[8];
        #pragma unroll
        for (int nf = 0; nf < 8; ++nf) {
            int col = n0 + nf * 16 + l15;
            s2v[nf] = s2[col]; t2v[nf] = t2[col]; w3v[nf] = W3[col];
        }
        #pragma unroll
        for (int mf = 0; mf < 4; ++mf)
            #pragma unroll
            for (int nf = 0; nf < 8; ++nf)
                #pragma unroll
                for (int i = 0; i < 4; ++i) {
                    float h = fmaxf(acc2[mf][nf][i] * s2v[nf] + t2v[nf], 0.0f);
                    part[mf * 4 + i] += h * w3v[nf];
                }
    }
    #pragma unroll
    for (int off = 1; off < 16; off <<= 1)
        #pragma unroll
        for (int i = 0; i < 16; ++i) part[i] += __shfl_xor(part[i], off, 64);

    __syncthreads();
    if (l15 == 0) {
        #pragma unroll
        for (int mf = 0; mf < 4; ++mf)
            #pragma unroll
            for (int i = 0; i < 4; ++i)
                outb[w * 64 + mf * 16 + lq * 4 + i] = part[mf * 4 + i];
    }
    __syncthreads();
    if (tidx < 64) {
        float r = outb[tidx] + outb[64 + tidx] + outb[128 + tidx] + outb[192 + tidx] + b3[0];
        out[m0 + tidx] = r;
    }
}

extern "C" void kernel_launch(void* const* d_in, const int* in_sizes, int n_in,
                              void* d_out, int out_size, void* d_ws, size_t ws_size,
                              hipStream_t stream)
{
    const float* feat = (const float*)d_in[0];
    const float* qp   = (const float*)d_in[1];
    const float* W1   = (const float*)d_in[2];
    const float* b1   = (const float*)d_in[3];
    const float* g1   = (const float*)d_in[4];
    const float* be1  = (const float*)d_in[5];
    const float* m1   = (const float*)d_in[6];
    const float* v1   = (const float*)d_in[7];
    const float* W2   = (const float*)d_in[8];
    const float* b2   = (const float*)d_in[9];
    const float* g2   = (const float*)d_in[10];
    const float* be2  = (const float*)d_in[11];
    const float* m2   = (const float*)d_in[12];
    const float* v2   = (const float*)d_in[13];
    const float* W3   = (const float*)d_in[14];
    const float* b3   = (const float*)d_in[15];

    char* ws = (char*)d_ws;
    u16*   W1t   = (u16*)(ws);                    // 131072 B
    u16*   W2t   = (u16*)(ws + 131072);           // 524288 B
    float* s1    = (float*)(ws + 655360);
    float* t1    = (float*)(ws + 657408);
    float* s2    = (float*)(ws + 659456);
    float* t2    = (float*)(ws + 661504);
    u16*   feats = (u16*)(ws + 663552);           // 33554432 B
    u16*   featT = (u16*)(ws + 663552 + 33554432);// 134217728 B
    const size_t needed = 663552 + 33554432 + 134217728;

    prep_kernel<<<1024, 256, 0, stream>>>(W1, W2, b1, g1, be1, m1, v1,
                                          b2, g2, be2, m2, v2,
                                          W1t, W2t, s1, t1, s2, t2);
    if (ws_size >= needed) {
        transpose_kernel<<<16384, 256, 0, stream>>>(feat, featT);
        sampleT_kernel<<<(MTOT * 64) / 256, 256, 0, stream>>>(featT, qp, feats);
    } else {
        sample_kernel<<<(MTOT * 128) / 256, 256, 0, stream>>>(feat, qp, feats);
    }
    mlp_kernel<<<MTOT / 64, 256, 0, stream>>>(feats, W1t, W2t, s1, t1, s2, t2,
                                              W3, b3, (float*)d_out);
}

// Round 3
// 205.274 us; speedup vs baseline: 6.7696x; 1.4696x over previous
//
#include <hip/hip_runtime.h>
#include <hip/hip_bf16.h>

using bf16x8 = __attribute__((ext_vector_type(8))) short;
using f32x4  = __attribute__((ext_vector_type(4))) float;
typedef unsigned short u16;
typedef unsigned int u32;

#define NB    2
#define NC    128
#define NPTS  65536
#define MTOT  (NB*NPTS)     // 131072

// round-to-nearest-even fp32 -> bf16 (bit pattern)
static __device__ __forceinline__ u16 f2bf(float f) {
    u32 u = __float_as_uint(f);
    u32 r = (u + 0x7FFFu + ((u >> 16) & 1u)) >> 16;
    return (u16)r;
}
static __device__ __forceinline__ float bflo(u32 d) { return __uint_as_float(d << 16); }
static __device__ __forceinline__ float bfhi(u32 d) { return __uint_as_float(d & 0xFFFF0000u); }

// ---------------- prep: pack weights fragment-major, fold BN ----------------
// W1p[((t*4+kk)*8+nf)*512 + l*8 + j]  = W1[kk*32+(l>>4)*8+j][t*128+nf*16+(l&15)]
// W2p[((t*16+kk)*8+nf)*512 + l*8 + j] = W2[kk*32+(l>>4)*8+j][t*128+nf*16+(l&15)]
__global__ void prep_kernel(
    const float* __restrict__ W1, const float* __restrict__ W2,
    const float* __restrict__ b1, const float* __restrict__ g1, const float* __restrict__ be1,
    const float* __restrict__ m1, const float* __restrict__ v1,
    const float* __restrict__ b2, const float* __restrict__ g2, const float* __restrict__ be2,
    const float* __restrict__ m2, const float* __restrict__ v2,
    u16* __restrict__ W1p, u16* __restrict__ W2p,
    float* __restrict__ s1, float* __restrict__ t1,
    float* __restrict__ s2, float* __restrict__ t2)
{
    int id = blockIdx.x * 256 + threadIdx.x;          // 0 .. 32767
    {   // W2p: one 8-elem fragment chunk per thread
        int l = id & 63, nf = (id >> 6) & 7, kk = (id >> 9) & 15, t = id >> 13;
        int n  = t * 128 + nf * 16 + (l & 15);
        int c0 = kk * 32 + (l >> 4) * 8;
        #pragma unroll
        for (int j = 0; j < 8; ++j)
            W2p[id * 8 + j] = f2bf(W2[(size_t)(c0 + j) * 512 + n]);
    }
    if (id < 8192) {   // W1p
        int l = id & 63, nf = (id >> 6) & 7, kk = (id >> 9) & 3, t = id >> 11;
        int n  = t * 128 + nf * 16 + (l & 15);
        int c0 = kk * 32 + (l >> 4) * 8;
        #pragma unroll
        for (int j = 0; j < 8; ++j)
            W1p[id * 8 + j] = f2bf(W1[(size_t)(c0 + j) * 512 + n]);
    }
    if (id < 512) {
        float s = g1[id] * rsqrtf(v1[id] + 1e-5f);
        s1[id] = s;
        t1[id] = (b1[id] - m1[id]) * s + be1[id];
        float ss = g2[id] * rsqrtf(v2[id] + 1e-5f);
        s2[id] = ss;
        t2[id] = (b2[id] - m2[id]) * ss + be2[id];
    }
}

// ---------------- volume transpose: (B,C,64^3) f32 -> (B,64^3,C) bf16 ----------------
__global__ __launch_bounds__(256) void transpose_kernel(const float* __restrict__ feat,
                                                        u16* __restrict__ featT)
{
    __shared__ float tile[128][33];
    int blk = blockIdx.x;               // 0..16383
    int b   = blk >> 13;
    int v0  = (blk & 8191) << 5;
    int t   = threadIdx.x;
    int vi  = t & 31;
    int c0  = t >> 5;
    const float* fb = feat + ((size_t)b << 25);
    #pragma unroll
    for (int r = 0; r < 16; ++r) {
        int c = c0 + 8 * r;
        tile[c][vi] = fb[((size_t)c << 18) + v0 + vi];
    }
    __syncthreads();
    u32* outp = (u32*)(featT + (((size_t)b << 18) + v0) * 128);
    #pragma unroll
    for (int r = 0; r < 8; ++r) {
        int w  = t + 256 * r;
        int v  = w >> 6;
        int cp = w & 63;
        float lo = tile[2 * cp][v], hi = tile[2 * cp + 1][v];
        outp[w] = (u32)f2bf(lo) | ((u32)f2bf(hi) << 16);
    }
}

// ---------------- trilinear sampling, channel-last ----------------
__global__ __launch_bounds__(256) void sampleT_kernel(const u16* __restrict__ featT,
                                                      const float* __restrict__ qp,
                                                      u16* __restrict__ fo)
{
    int tid = blockIdx.x * 256 + threadIdx.x;
    int p   = tid >> 6;
    int cp  = tid & 63;
    int b   = p >> 16;

    float qx = qp[p * 3 + 0];
    float qy = qp[p * 3 + 1];
    float qz = qp[p * 3 + 2];
    float x = fminf(fmaxf(qx * 63.0f, 0.0f), 63.0f);
    float y = fminf(fmaxf(qy * 63.0f, 0.0f), 63.0f);
    float z = fminf(fmaxf(qz * 63.0f, 0.0f), 63.0f);
    int x0 = (int)floorf(x), y0 = (int)floorf(y), z0 = (int)floorf(z);
    int x1 = min(x0 + 1, 63), y1 = min(y0 + 1, 63), z1 = min(z0 + 1, 63);
    float wx = x - (float)x0, wy = y - (float)y0, wz = z - (float)z0;

    const u32* fb = (const u32*)featT + (((size_t)b << 18) << 6);
    int zy00 = z0 * 4096 + y0 * 64, zy01 = z0 * 4096 + y1 * 64;
    int zy10 = z1 * 4096 + y0 * 64, zy11 = z1 * 4096 + y1 * 64;
    u32 d000 = fb[(size_t)(zy00 + x0) * 64 + cp];
    u32 d001 = fb[(size_t)(zy00 + x1) * 64 + cp];
    u32 d010 = fb[(size_t)(zy01 + x0) * 64 + cp];
    u32 d011 = fb[(size_t)(zy01 + x1) * 64 + cp];
    u32 d100 = fb[(size_t)(zy10 + x0) * 64 + cp];
    u32 d101 = fb[(size_t)(zy10 + x1) * 64 + cp];
    u32 d110 = fb[(size_t)(zy11 + x0) * 64 + cp];
    u32 d111 = fb[(size_t)(zy11 + x1) * 64 + cp];

    float omx = 1.0f - wx, omy = 1.0f - wy, omz = 1.0f - wz;
    float rl, rh;
    {
        float c00 = bflo(d000) * omx + bflo(d001) * wx;
        float c01 = bflo(d010) * omx + bflo(d011) * wx;
        float c10 = bflo(d100) * omx + bflo(d101) * wx;
        float c11 = bflo(d110) * omx + bflo(d111) * wx;
        rl = (c00 * omy + c01 * wy) * omz + (c10 * omy + c11 * wy) * wz;
    }
    {
        float c00 = bfhi(d000) * omx + bfhi(d001) * wx;
        float c01 = bfhi(d010) * omx + bfhi(d011) * wx;
        float c10 = bfhi(d100) * omx + bfhi(d101) * wx;
        float c11 = bfhi(d110) * omx + bfhi(d111) * wx;
        rh = (c00 * omy + c01 * wy) * omz + (c10 * omy + c11 * wy) * wz;
    }
    ((u32*)fo)[(size_t)p * 64 + cp] = (u32)f2bf(rl) | ((u32)f2bf(rh) << 16);
}

// ---------------- fused MLP, software-pipelined ----------------
__global__ __launch_bounds__(256, 2) void mlp_kernel(
    const u16* __restrict__ feats, const u16* __restrict__ W1p, const u16* __restrict__ W2p,
    const float* __restrict__ s1, const float* __restrict__ t1,
    const float* __restrict__ s2, const float* __restrict__ t2,
    const float* __restrict__ W3, const float* __restrict__ b3,
    float* __restrict__ out)
{
    __shared__ u16 h1[64 * 512];      // 64 KiB
    __shared__ float outb[256];       // 1 KiB

    const int tidx = threadIdx.x;
    const int w    = tidx >> 6;
    const int l    = tidx & 63;
    const int l15  = l & 15;
    const int lq   = l >> 4;
    const int m0   = blockIdx.x * 64;
    const int n0   = w * 128;

    const u16* B1 = W1p + (size_t)(w * 4)  * 8 * 512;   // per-wave packed W1 panel
    const u16* B2 = W2p + (size_t)(w * 16) * 8 * 512;   // per-wave packed W2 panel

#define LOADA1(dst, kk) { _Pragma("unroll") for (int mf = 0; mf < 4; ++mf) \
    (dst)[mf] = *(const bf16x8*)(feats + (size_t)(m0 + mf * 16 + l15) * 128 + (kk) * 32 + lq * 8); }
#define LOADB1(dst, kk) { _Pragma("unroll") for (int nf = 0; nf < 8; ++nf) \
    (dst)[nf] = *(const bf16x8*)(B1 + ((kk) * 8 + nf) * 512 + l * 8); }
#define LOADB2(dst, kk) { _Pragma("unroll") for (int nf = 0; nf < 8; ++nf) \
    (dst)[nf] = *(const bf16x8*)(B2 + ((kk) * 8 + nf) * 512 + l * 8); }
#define LOADA2(dst, kk) { _Pragma("unroll") for (int mf = 0; mf < 4; ++mf) { \
    int row = mf * 16 + l15; \
    (dst)[mf] = *(const bf16x8*)(h1 + row * 512 + (((kk) * 32 + lq * 8) ^ ((row & 7) << 3))); } }

    // ---- GEMM1: feats(64x128) @ W1 -> acc, 2-deep pipeline over 4 k-steps ----
    f32x4 acc[4][8];
    #pragma unroll
    for (int i = 0; i < 4; ++i)
        #pragma unroll
        for (int j = 0; j < 8; ++j) acc[i][j] = (f32x4){0.f, 0.f, 0.f, 0.f};

    {
        bf16x8 a[2][4], b[2][8];
        LOADA1(a[0], 0); LOADB1(b[0], 0);
        #pragma unroll
        for (int kk = 0; kk < 4; ++kk) {
            const int cur = kk & 1, nxt = cur ^ 1;
            if (kk < 3) { LOADA1(a[nxt], kk + 1); LOADB1(b[nxt], kk + 1); }
            __builtin_amdgcn_s_setprio(1);
            #pragma unroll
            for (int mf = 0; mf < 4; ++mf)
                #pragma unroll
                for (int nf = 0; nf < 8; ++nf)
                    acc[mf][nf] = __builtin_amdgcn_mfma_f32_16x16x32_bf16(a[cur][mf], b[cur][nf], acc[mf][nf], 0, 0, 0);
            __builtin_amdgcn_s_setprio(0);
        }
    }

    // ---- prefetch GEMM2's first B panel (independent of h1) ----
    bf16x8 pb[2][8];
    LOADB2(pb[0], 0);

    // ---- BN1 + ReLU -> h1 in LDS (XOR-swizzled 16B chunks) ----
    {
        float s1v[8], t1v[8];
        #pragma unroll
        for (int nf = 0; nf < 8; ++nf) {
            int col = n0 + nf * 16 + l15;
            s1v[nf] = s1[col]; t1v[nf] = t1[col];
        }
        #pragma unroll
        for (int mf = 0; mf < 4; ++mf)
            #pragma unroll
            for (int nf = 0; nf < 8; ++nf) {
                int col = n0 + nf * 16 + l15;
                #pragma unroll
                for (int i = 0; i < 4; ++i) {
                    int row = mf * 16 + lq * 4 + i;
                    float v = fmaxf(acc[mf][nf][i] * s1v[nf] + t1v[nf], 0.0f);
                    h1[row * 512 + (col ^ ((row & 7) << 3))] = f2bf(v);
                }
            }
    }
    __syncthreads();

    // ---- GEMM2: h1(64x512) @ W2 -> acc2, 16 k-steps, B 2-deep pipelined ----
    f32x4 acc2[4][8];
    #pragma unroll
    for (int i = 0; i < 4; ++i)
        #pragma unroll
        for (int j = 0; j < 8; ++j) acc2[i][j] = (f32x4){0.f, 0.f, 0.f, 0.f};

    #pragma unroll
    for (int kk = 0; kk < 16; ++kk) {
        const int cur = kk & 1, nxt = cur ^ 1;
        if (kk < 15) LOADB2(pb[nxt], kk + 1);
        bf16x8 a2[4];
        LOADA2(a2, kk);
        __builtin_amdgcn_s_setprio(1);
        #pragma unroll
        for (int mf = 0; mf < 4; ++mf)
            #pragma unroll
            for (int nf = 0; nf < 8; ++nf)
                acc2[mf][nf] = __builtin_amdgcn_mfma_f32_16x16x32_bf16(a2[mf], pb[cur][nf], acc2[mf][nf], 0, 0, 0);
        __builtin_amdgcn_s_setprio(0);
    }

    // ---- BN2 + ReLU + final dot with W3 (fp32) ----
    float part[16];
    #pragma unroll
    for (int i = 0; i < 16; ++i) part[i] = 0.f;
    {
        float s2v[8], t2v[8], w3v[8];
        #pragma unroll
        for (int nf = 0; nf < 8; ++nf) {
            int col = n0 + nf * 16 + l15;
            s2v[nf] = s2[col]; t2v[nf] = t2[col]; w3v[nf] = W3[col];
        }
        #pragma unroll
        for (int mf = 0; mf < 4; ++mf)
            #pragma unroll
            for (int nf = 0; nf < 8; ++nf)
                #pragma unroll
                for (int i = 0; i < 4; ++i) {
                    float h = fmaxf(acc2[mf][nf][i] * s2v[nf] + t2v[nf], 0.0f);
                    part[mf * 4 + i] += h * w3v[nf];
                }
    }
    #pragma unroll
    for (int off = 1; off < 16; off <<= 1)
        #pragma unroll
        for (int i = 0; i < 16; ++i) part[i] += __shfl_xor(part[i], off, 64);

    if (l15 == 0) {
        #pragma unroll
        for (int mf = 0; mf < 4; ++mf)
            #pragma unroll
            for (int i = 0; i < 4; ++i)
                outb[w * 64 + mf * 16 + lq * 4 + i] = part[mf * 4 + i];
    }
    __syncthreads();
    if (tidx < 64) {
        float r = outb[tidx] + outb[64 + tidx] + outb[128 + tidx] + outb[192 + tidx] + b3[0];
        out[m0 + tidx] = r;
    }
#undef LOADA1
#undef LOADB1
#undef LOADB2
#undef LOADA2
}

// ---------------- fallback scattered sampler (if ws too small) ----------------
__global__ void sample_kernel(const float* __restrict__ feat,
                              const float* __restrict__ qp,
                              u16* __restrict__ fo)
{
    int tid = blockIdx.x * 256 + threadIdx.x;
    int p = tid >> 7;
    int c = tid & 127;
    int b = p >> 16;

    float qx = qp[p * 3 + 0], qy = qp[p * 3 + 1], qz = qp[p * 3 + 2];
    float x = fminf(fmaxf(qx * 63.0f, 0.0f), 63.0f);
    float y = fminf(fmaxf(qy * 63.0f, 0.0f), 63.0f);
    float z = fminf(fmaxf(qz * 63.0f, 0.0f), 63.0f);
    int x0 = (int)floorf(x), y0 = (int)floorf(y), z0 = (int)floorf(z);
    int x1 = min(x0 + 1, 63), y1 = min(y0 + 1, 63), z1 = min(z0 + 1, 63);
    float wx = x - (float)x0, wy = y - (float)y0, wz = z - (float)z0;

    const float* fb = feat + ((size_t)(b * NC + c) << 18);
    int zy00 = z0 * 4096 + y0 * 64, zy01 = z0 * 4096 + y1 * 64;
    int zy10 = z1 * 4096 + y0 * 64, zy11 = z1 * 4096 + y1 * 64;
    float f000 = fb[zy00 + x0], f001 = fb[zy00 + x1];
    float f010 = fb[zy01 + x0], f011 = fb[zy01 + x1];
    float f100 = fb[zy10 + x0], f101 = fb[zy10 + x1];
    float f110 = fb[zy11 + x0], f111 = fb[zy11 + x1];

    float omx = 1.0f - wx;
    float c00 = f000 * omx + f001 * wx;
    float c01 = f010 * omx + f011 * wx;
    float c10 = f100 * omx + f101 * wx;
    float c11 = f110 * omx + f111 * wx;
    float omy = 1.0f - wy;
    float c0 = c00 * omy + c01 * wy;
    float c1 = c10 * omy + c11 * wy;
    float v  = c0 * (1.0f - wz) + c1 * wz;
    fo[(size_t)p * 128 + c] = f2bf(v);
}

extern "C" void kernel_launch(void* const* d_in, const int* in_sizes, int n_in,
                              void* d_out, int out_size, void* d_ws, size_t ws_size,
                              hipStream_t stream)
{
    const float* feat = (const float*)d_in[0];
    const float* qp   = (const float*)d_in[1];
    const float* W1   = (const float*)d_in[2];
    const float* b1   = (const float*)d_in[3];
    const float* g1   = (const float*)d_in[4];
    const float* be1  = (const float*)d_in[5];
    const float* m1   = (const float*)d_in[6];
    const float* v1   = (const float*)d_in[7];
    const float* W2   = (const float*)d_in[8];
    const float* b2   = (const float*)d_in[9];
    const float* g2   = (const float*)d_in[10];
    const float* be2  = (const float*)d_in[11];
    const float* m2   = (const float*)d_in[12];
    const float* v2   = (const float*)d_in[13];
    const float* W3   = (const float*)d_in[14];
    const float* b3   = (const float*)d_in[15];

    char* ws = (char*)d_ws;
    u16*   W1p   = (u16*)(ws);                    // 131072 B
    u16*   W2p   = (u16*)(ws + 131072);           // 524288 B
    float* s1    = (float*)(ws + 655360);
    float* t1    = (float*)(ws + 657408);
    float* s2    = (float*)(ws + 659456);
    float* t2    = (float*)(ws + 661504);
    u16*   feats = (u16*)(ws + 663552);           // 33554432 B
    u16*   featT = (u16*)(ws + 663552 + 33554432);// 134217728 B
    const size_t needed = 663552 + 33554432 + 134217728;

    prep_kernel<<<128, 256, 0, stream>>>(W1, W2, b1, g1, be1, m1, v1,
                                         b2, g2, be2, m2, v2,
                                         W1p, W2p, s1, t1, s2, t2);
    if (ws_size >= needed) {
        transpose_kernel<<<16384, 256, 0, stream>>>(feat, featT);
        sampleT_kernel<<<(MTOT * 64) / 256, 256, 0, stream>>>(featT, qp, feats);
    } else {
        sample_kernel<<<(MTOT * 128) / 256, 256, 0, stream>>>(feat, qp, feats);
    }
    mlp_kernel<<<MTOT / 64, 256, 0, stream>>>(feats, W1p, W2p, s1, t1, s2, t2,
                                              W3, b3, (float*)d_out);
}